// Round 2
// baseline (242.095 us; speedup 1.0000x reference)
//
#include <hip/hip_runtime.h>
#include <cmath>

#define NK 1024
#define ND 64
#define NB 32
#define NH 64
#define NW 64
#define NTOT (NB*NH*NW)   // 131072 query vectors

// d_ws layout: [0..1023] uint32 counts, [1024..2047] float cnorm

__global__ __launch_bounds__(1024) void vq_prep(const float* __restrict__ emb,
                                                unsigned int* __restrict__ counts,
                                                float* __restrict__ cnorm) {
    int k = threadIdx.x;  // 1024 threads, one per code
    counts[k] = 0u;
    const float4* row = reinterpret_cast<const float4*>(emb + (size_t)k * ND);
    float s = 0.0f;
#pragma unroll
    for (int i = 0; i < ND/4; ++i) {
        float4 v = row[i];
        s += v.x*v.x + v.y*v.y + v.z*v.z + v.w*v.w;
    }
    cnorm[k] = s;
}

__global__ __launch_bounds__(256) void vq_main(const float* __restrict__ in,
                                               const float* __restrict__ emb,
                                               const float* __restrict__ cnorm,
                                               unsigned int* __restrict__ counts,
                                               float* __restrict__ out_idx,
                                               float* __restrict__ out_q) {
    // Xs[q=w][d=c], Es[k][d]; pad 64->68 floats: row stride 272B keeps float4
    // reads 16B-aligned, bank clusters spaced by 4 -> <=2-way conflicts (free).
    __shared__ float Xs[64][68];
    __shared__ float Es[64][68];
    __shared__ int bidx_lds[64];

    const int blk = blockIdx.x;   // b*64 + h
    const int b = blk >> 6;
    const int h = blk & 63;
    const int tid = threadIdx.x;
    const int tk = tid & 15;      // code group   (16)
    const int tq = tid >> 4;      // query group  (16)

    // ---- stage X tile: Xs[w][c] = in[b, c, h, w], coalesced over w ----
    {
        const int w = tid & 63;
        const int c0 = tid >> 6;
        const float* base = in + (size_t)b * (64*64*64) + (size_t)h * 64 + w;
#pragma unroll
        for (int p = 0; p < 16; ++p) {
            int c = c0 + p*4;
            Xs[w][c] = base[(size_t)c * 4096];
        }
    }

    float best[4];
    int   bi[4];
#pragma unroll
    for (int i = 0; i < 4; ++i) { best[i] = 3.4e38f; bi[i] = 0; }

    for (int ch = 0; ch < 16; ++ch) {
        const int kc = ch * 64;
        // ---- stage 64-code chunk: Es[kl][d] (coalesced float4 over d) ----
        {
            const int d4 = (tid & 15) * 4;
            const int kl0 = tid >> 4;
#pragma unroll
            for (int p = 0; p < 4; ++p) {
                int kl = kl0 + p*16;
                float4 v = *reinterpret_cast<const float4*>(emb + (size_t)(kc + kl) * ND + d4);
                *reinterpret_cast<float4*>(&Es[kl][d4]) = v;
            }
        }
        __syncthreads();

        float dot[4][4];
#pragma unroll
        for (int i = 0; i < 4; ++i)
#pragma unroll
            for (int j = 0; j < 4; ++j) dot[i][j] = 0.0f;

#pragma unroll
        for (int d4 = 0; d4 < 16; ++d4) {
            float4 xq[4], ek[4];
#pragma unroll
            for (int i = 0; i < 4; ++i)
                xq[i] = *reinterpret_cast<const float4*>(&Xs[tq + 16*i][d4*4]);
#pragma unroll
            for (int j = 0; j < 4; ++j)
                ek[j] = *reinterpret_cast<const float4*>(&Es[tk + 16*j][d4*4]);
#pragma unroll
            for (int i = 0; i < 4; ++i)
#pragma unroll
                for (int j = 0; j < 4; ++j) {
                    dot[i][j] = fmaf(xq[i].x, ek[j].x, dot[i][j]);
                    dot[i][j] = fmaf(xq[i].y, ek[j].y, dot[i][j]);
                    dot[i][j] = fmaf(xq[i].z, ek[j].z, dot[i][j]);
                    dot[i][j] = fmaf(xq[i].w, ek[j].w, dot[i][j]);
                }
        }

        // ---- distance + running argmin (codes ascending: first-min wins) ----
#pragma unroll
        for (int j = 0; j < 4; ++j) {
            const int k = kc + tk + 16*j;
            const float cn = cnorm[k];
#pragma unroll
            for (int i = 0; i < 4; ++i) {
                float dist = cn - 2.0f * dot[i][j];
                if (dist < best[i]) { best[i] = dist; bi[i] = k; }
            }
        }
        __syncthreads();  // before next chunk overwrites Es
    }

    // ---- reduce over the 16 tk lanes sharing each query set ----
#pragma unroll
    for (int m = 1; m < 16; m <<= 1) {
#pragma unroll
        for (int i = 0; i < 4; ++i) {
            float ob = __shfl_xor(best[i], m, 64);
            int   oi = __shfl_xor(bi[i], m, 64);
            if (ob < best[i] || (ob == best[i] && oi < bi[i])) { best[i] = ob; bi[i] = oi; }
        }
    }
    if (tk == 0) {
#pragma unroll
        for (int i = 0; i < 4; ++i) bidx_lds[tq + 16*i] = bi[i];
    }
    __syncthreads();

    // ---- indices (as float) + histogram ----
    if (tid < 64) {
        int idx = bidx_lds[tid];
        out_idx[(size_t)blk * 64 + tid] = (float)idx;
        atomicAdd(&counts[idx], 1u);
    }

    // ---- quantized in (B,C,H,W): coalesced over w, gather rows from L2 ----
    {
        const int w = tid & 63;
        const int c0 = tid >> 6;
        const int idx = bidx_lds[w];
        const float* erow = emb + (size_t)idx * ND;
        float* baseo = out_q + (size_t)b * (64*64*64) + (size_t)h * 64 + w;
#pragma unroll
        for (int p = 0; p < 16; ++p) {
            int c = c0 + p*4;
            baseo[(size_t)c * 4096] = erow[c];
        }
    }
}

__global__ __launch_bounds__(1024) void vq_perp(const unsigned int* __restrict__ counts,
                                                float* __restrict__ out_p) {
    __shared__ float red[16];
    int tid = threadIdx.x;  // 1024
    float p = (float)counts[tid] * (1.0f / (float)NTOT);
    float t = p * logf(p + 1e-10f);
#pragma unroll
    for (int m = 1; m < 64; m <<= 1) t += __shfl_xor(t, m, 64);
    if ((tid & 63) == 0) red[tid >> 6] = t;
    __syncthreads();
    if (tid < 16) {
        float s = red[tid];
#pragma unroll
        for (int m = 1; m < 16; m <<= 1) s += __shfl_xor(s, m, 64);
        if (tid == 0) out_p[0] = expf(-s);
    }
}

extern "C" void kernel_launch(void* const* d_in, const int* in_sizes, int n_in,
                              void* d_out, int out_size, void* d_ws, size_t ws_size,
                              hipStream_t stream) {
    const float* in  = (const float*)d_in[0];   // (32, 64, 64, 64)
    const float* emb = (const float*)d_in[1];   // (1024, 64)
    float* out = (float*)d_out;

    unsigned int* counts = (unsigned int*)d_ws;
    float* cnorm = (float*)d_ws + NK;

    float* out_idx = out;                       // 131072
    float* out_q   = out + NTOT;                // 8388608
    float* out_p   = out + NTOT + (size_t)NTOT * ND;  // 1

    vq_prep<<<1, 1024, 0, stream>>>(emb, counts, cnorm);
    vq_main<<<NB*NH, 256, 0, stream>>>(in, emb, cnorm, counts, out_idx, out_q);
    vq_perp<<<1, 1024, 0, stream>>>(counts, out_p);
}